// Round 2
// baseline (84658.893 us; speedup 1.0000x reference)
//
#include <hip/hip_runtime.h>

#define HH 1024
#define TT 4096
#define NWG 256
#define NWG_PER_LAYER 128
#define JS_PER_WG 8     // 1024 / 128
#define JS_PER_WAVE 2   // 8 j's / 4 waves

__device__ __forceinline__ float fsigmoid(float x) {
    return 1.0f / (1.0f + __expf(-x));
}
__device__ __forceinline__ float ftanh(float x) {
    float ax = fabsf(x);
    float e = __expf(-2.0f * ax);
    float t = (1.0f - e) / (1.0f + e);
    return copysignf(t, x);
}
__device__ __forceinline__ void fma4(float& a, const float4 w, const float4 v) {
    a = fmaf(w.x, v.x, a);
    a = fmaf(w.y, v.y, a);
    a = fmaf(w.z, v.z, a);
    a = fmaf(w.w, v.w, a);
}

// Persistent 2-layer LSTM, layers pipelined with skew 1.
// WGs [0,128): layer 0.  WGs [128,256): layer 1.
// Each WG owns 8 j-rows of h; each wave owns 2 j's (8 gate rows across
// w_ih+w_hh register-resident: 2j * 4 gates * 2 mats * 16 floats = 256 VGPRs).
// Grid sync: monotonic agent-scope atomic counter (all 256 WGs co-resident:
// 1 block/CU at __launch_bounds__(256,1), grid == CU count).
__global__ __launch_bounds__(256, 1) void lstm2_persistent(
    const float* __restrict__ x,
    const float* __restrict__ wih0, const float* __restrict__ whh0,
    const float* __restrict__ bih0, const float* __restrict__ bhh0,
    const float* __restrict__ wih1, const float* __restrict__ whh1,
    const float* __restrict__ bih1, const float* __restrict__ bhh1,
    float* __restrict__ out,    // [T][H]  h2 (output + h2 recurrence buffer)
    float* __restrict__ ring,   // [2][H]  h1 ring (layer0 -> layer1)
    unsigned* __restrict__ barcnt)  // barrier counter (zeroed per call)
{
    const int wg   = blockIdx.x;
    const int tid  = threadIdx.x;
    const int wave = tid >> 6;
    const int lane = tid & 63;
    const bool isL1 = (wg >= NWG_PER_LAYER);
    const int wgl   = isL1 ? (wg - NWG_PER_LAYER) : wg;
    const int jbase = wgl * JS_PER_WG + wave * JS_PER_WAVE;
    const int col   = lane * 16;   // this lane's 16-elem chunk of the 1024-vector

    const float* wih = isL1 ? wih1 : wih0;
    const float* whh = isL1 ? whh1 : whh0;
    const float* bih = isL1 ? bih1 : bih0;
    const float* bhh = isL1 ? bhh1 : bhh0;

    // ---- one-time weight preload into registers ----
    float4 Wih[8][4];
    float4 Whh[8][4];
    float  bias[8];
    #pragma unroll
    for (int jj = 0; jj < JS_PER_WAVE; ++jj) {
        #pragma unroll
        for (int g = 0; g < 4; ++g) {
            const int r   = jj * 4 + g;
            const int row = g * HH + (jbase + jj);
            const float4* pi = (const float4*)(wih + (size_t)row * HH + col);
            const float4* ph = (const float4*)(whh + (size_t)row * HH + col);
            #pragma unroll
            for (int q = 0; q < 4; ++q) { Wih[r][q] = pi[q]; Whh[r][q] = ph[q]; }
            bias[r] = bih[row] + bhh[row];
        }
    }

    float c[JS_PER_WAVE] = {0.0f, 0.0f};

    for (int k = 0; k <= TT; ++k) {
        const int t = isL1 ? (k - 1) : k;
        if (t >= 0 && t < TT) {
            // input vector: layer0 reads x[t]; layer1 reads h1[t] from the ring
            const float* inv = isL1 ? (ring + (size_t)(t & 1) * HH)
                                    : (x    + (size_t)t * HH);
            float4 in4[4];
            {
                const float4* p = (const float4*)(inv + col);
                #pragma unroll
                for (int q = 0; q < 4; ++q) in4[q] = p[q];
            }

            float acc[8];
            #pragma unroll
            for (int r = 0; r < 8; ++r) acc[r] = 0.0f;

            #pragma unroll
            for (int r = 0; r < 8; ++r)
                #pragma unroll
                for (int q = 0; q < 4; ++q) fma4(acc[r], Wih[r][q], in4[q]);

            if (t > 0) {
                // recurrent vector: layer0 -> h1[t-1] (ring), layer1 -> h2[t-1] (out)
                const float* hpv = isL1 ? (out  + (size_t)(t - 1) * HH)
                                        : (ring + (size_t)((t - 1) & 1) * HH);
                float4 hp4[4];
                {
                    const float4* p = (const float4*)(hpv + col);
                    #pragma unroll
                    for (int q = 0; q < 4; ++q) hp4[q] = p[q];
                }
                #pragma unroll
                for (int r = 0; r < 8; ++r)
                    #pragma unroll
                    for (int q = 0; q < 4; ++q) fma4(acc[r], Whh[r][q], hp4[q]);
            }

            // butterfly reduce all 8 accumulators across 64 lanes
            #pragma unroll
            for (int m = 1; m < 64; m <<= 1)
                #pragma unroll
                for (int r = 0; r < 8; ++r)
                    acc[r] += __shfl_xor(acc[r], m, 64);

            // gates (PyTorch order i,f,g,o); every lane computes redundantly
            #pragma unroll
            for (int jj = 0; jj < JS_PER_WAVE; ++jj) {
                const float gi = fsigmoid(acc[jj * 4 + 0] + bias[jj * 4 + 0]);
                const float gf = fsigmoid(acc[jj * 4 + 1] + bias[jj * 4 + 1]);
                const float gg = ftanh   (acc[jj * 4 + 2] + bias[jj * 4 + 2]);
                const float go = fsigmoid(acc[jj * 4 + 3] + bias[jj * 4 + 3]);
                c[jj] = gf * c[jj] + gi * gg;
                const float h = go * ftanh(c[jj]);
                if (lane == 0) {
                    if (isL1) out [(size_t)t * HH + jbase + jj] = h;
                    else      ring[(size_t)(t & 1) * HH + jbase + jj] = h;
                }
            }
        }

        // ---- grid barrier (monotonic epoch counter, agent scope) ----
        if (k < TT) {
            __syncthreads();   // all 4 waves drain their stores (vmcnt) + arrive
            if (tid == 0) {
                __threadfence();   // release: flush this XCD's L2 to coherence point
                __hip_atomic_fetch_add(barcnt, 1u, __ATOMIC_ACQ_REL,
                                       __HIP_MEMORY_SCOPE_AGENT);
                const unsigned target = (unsigned)(k + 1) * NWG;
                while (__hip_atomic_load(barcnt, __ATOMIC_ACQUIRE,
                                         __HIP_MEMORY_SCOPE_AGENT) < target)
                    __builtin_amdgcn_s_sleep(2);
                __threadfence();   // acquire: invalidate local L1/L2
            }
            __syncthreads();
        }
    }
}

extern "C" void kernel_launch(void* const* d_in, const int* in_sizes, int n_in,
                              void* d_out, int out_size, void* d_ws, size_t ws_size,
                              hipStream_t stream) {
    (void)in_sizes; (void)n_in; (void)out_size; (void)ws_size;
    const float* x    = (const float*)d_in[0];
    const float* wih0 = (const float*)d_in[1];
    const float* whh0 = (const float*)d_in[2];
    const float* bih0 = (const float*)d_in[3];
    const float* bhh0 = (const float*)d_in[4];
    const float* wih1 = (const float*)d_in[5];
    const float* whh1 = (const float*)d_in[6];
    const float* bih1 = (const float*)d_in[7];
    const float* bhh1 = (const float*)d_in[8];
    float* out = (float*)d_out;

    unsigned* barcnt = (unsigned*)d_ws;                   // [0, 256) bytes
    float*    ring   = (float*)((char*)d_ws + 256);       // 2 * 1024 * 4 B

    // zero the barrier counter every call (graph-capturable, stream-ordered)
    hipMemsetAsync(d_ws, 0, 256, stream);

    hipLaunchKernelGGL(lstm2_persistent, dim3(NWG), dim3(256), 0, stream,
                       x, wih0, whh0, bih0, bhh0,
                       wih1, whh1, bih1, bhh1, out, ring, barcnt);
}

// Round 3
// 82907.111 us; speedup vs baseline: 1.0211x; 1.0211x over previous
//
#include <hip/hip_runtime.h>

#define HH 1024
#define TT 4096
#define NWG 256
#define NWG_PER_LAYER 128
#define JS_PER_WG 8     // 1024 / 128
#define JS_PER_WAVE 2   // 8 j's / 4 waves

__device__ __forceinline__ float fsigmoid(float x) {
    return 1.0f / (1.0f + __expf(-x));
}
__device__ __forceinline__ float ftanh(float x) {
    float ax = fabsf(x);
    float e = __expf(-2.0f * ax);
    float t = (1.0f - e) / (1.0f + e);
    return copysignf(t, x);
}
__device__ __forceinline__ void fma4(float& a, const float4 w, const float4 v) {
    a = fmaf(w.x, v.x, a);
    a = fmaf(w.y, v.y, a);
    a = fmaf(w.z, v.z, a);
    a = fmaf(w.w, v.w, a);
}
// Make a register's value opaque so the compiler can neither rematerialize
// the load that produced it nor sink it into the loop. (learn_hip rule #17)
__device__ __forceinline__ void pin4(float4& v) {
    asm volatile("" : "+v"(v.x), "+v"(v.y), "+v"(v.z), "+v"(v.w));
}

// Persistent 2-layer LSTM, layers pipelined with skew 1.
// WGs [0,128): layer 0.  WGs [128,256): layer 1.
// Each WG owns 8 j-rows of h; each wave owns 2 j's; all 8 gate rows of both
// w_ih and w_hh are pinned register-resident (256 VGPRs of weights per lane).
// Grid sync: monotonic agent-scope atomic counter (all 256 WGs co-resident:
// 1 block/CU at __launch_bounds__(256,1), grid == CU count).
__global__ __launch_bounds__(256, 1) void lstm2_persistent(
    const float* __restrict__ x,
    const float* __restrict__ wih0, const float* __restrict__ whh0,
    const float* __restrict__ bih0, const float* __restrict__ bhh0,
    const float* __restrict__ wih1, const float* __restrict__ whh1,
    const float* __restrict__ bih1, const float* __restrict__ bhh1,
    float* __restrict__ out,    // [T][H]  h2 (output + h2 recurrence buffer)
    float* __restrict__ ring,   // [2][H]  h1 ring (layer0 -> layer1)
    unsigned* __restrict__ barcnt)  // barrier counter (zeroed per call)
{
    const int wg   = blockIdx.x;
    const int tid  = threadIdx.x;
    const int wave = tid >> 6;
    const int lane = tid & 63;
    const bool isL1 = (wg >= NWG_PER_LAYER);
    const int wgl   = isL1 ? (wg - NWG_PER_LAYER) : wg;
    const int jbase = wgl * JS_PER_WG + wave * JS_PER_WAVE;
    const int col   = lane * 16;   // this lane's 16-elem chunk of the 1024-vector

    const float* wih = isL1 ? wih1 : wih0;
    const float* whh = isL1 ? whh1 : whh0;
    const float* bih = isL1 ? bih1 : bih0;
    const float* bhh = isL1 ? bhh1 : bhh0;

    // ---- one-time weight preload into registers ----
    float4 Wih[8][4];
    float4 Whh[8][4];
    float  bias[8];
    #pragma unroll
    for (int jj = 0; jj < JS_PER_WAVE; ++jj) {
        #pragma unroll
        for (int g = 0; g < 4; ++g) {
            const int r   = jj * 4 + g;
            const int row = g * HH + (jbase + jj);
            const float4* pi = (const float4*)(wih + (size_t)row * HH + col);
            const float4* ph = (const float4*)(whh + (size_t)row * HH + col);
            #pragma unroll
            for (int q = 0; q < 4; ++q) { Wih[r][q] = pi[q]; Whh[r][q] = ph[q]; }
            bias[r] = bih[row] + bhh[row];
        }
    }
    // Pin every weight register: blocks rematerialization of the global loads
    // inside the timestep loop (round-2 failure mode: VGPR=160, 64 MB/step
    // re-read from LLC at ~20 us/step).
    #pragma unroll
    for (int r = 0; r < 8; ++r) {
        #pragma unroll
        for (int q = 0; q < 4; ++q) { pin4(Wih[r][q]); pin4(Whh[r][q]); }
        asm volatile("" : "+v"(bias[r]));
    }

    float c[JS_PER_WAVE] = {0.0f, 0.0f};

    const float* inv_base = isL1 ? ring : x;
    const size_t inv_stride_mask = isL1 ? 1u : 0xFFFFFFFFu;  // ring: t&1, x: t

    for (int k = 0; k <= TT; ++k) {
        const int t = isL1 ? (k - 1) : k;
        if (t >= 0 && t < TT) {
            // input vector: layer0 reads x[t]; layer1 reads h1[t] from the ring
            const size_t trow = (size_t)(t & inv_stride_mask);
            const float* inv = inv_base + trow * HH;
            float4 in4[4];
            {
                const float4* p = (const float4*)(inv + col);
                #pragma unroll
                for (int q = 0; q < 4; ++q) in4[q] = p[q];
            }

            float acc[8];
            #pragma unroll
            for (int r = 0; r < 8; ++r) acc[r] = 0.0f;

            #pragma unroll
            for (int r = 0; r < 8; ++r)
                #pragma unroll
                for (int q = 0; q < 4; ++q) fma4(acc[r], Wih[r][q], in4[q]);

            if (t > 0) {
                // recurrent vector: layer0 -> h1[t-1] (ring), layer1 -> h2[t-1] (out)
                const float* hpv = isL1 ? (out  + (size_t)(t - 1) * HH)
                                        : (ring + (size_t)((t - 1) & 1) * HH);
                float4 hp4[4];
                {
                    const float4* p = (const float4*)(hpv + col);
                    #pragma unroll
                    for (int q = 0; q < 4; ++q) hp4[q] = p[q];
                }
                #pragma unroll
                for (int r = 0; r < 8; ++r)
                    #pragma unroll
                    for (int q = 0; q < 4; ++q) fma4(acc[r], Whh[r][q], hp4[q]);
            }

            // butterfly reduce all 8 accumulators across 64 lanes
            #pragma unroll
            for (int m = 1; m < 64; m <<= 1)
                #pragma unroll
                for (int r = 0; r < 8; ++r)
                    acc[r] += __shfl_xor(acc[r], m, 64);

            // gates (PyTorch order i,f,g,o); every lane computes redundantly
            #pragma unroll
            for (int jj = 0; jj < JS_PER_WAVE; ++jj) {
                const float gi = fsigmoid(acc[jj * 4 + 0] + bias[jj * 4 + 0]);
                const float gf = fsigmoid(acc[jj * 4 + 1] + bias[jj * 4 + 1]);
                const float gg = ftanh   (acc[jj * 4 + 2] + bias[jj * 4 + 2]);
                const float go = fsigmoid(acc[jj * 4 + 3] + bias[jj * 4 + 3]);
                c[jj] = gf * c[jj] + gi * gg;
                const float h = go * ftanh(c[jj]);
                if (lane == 0) {
                    if (isL1) out [(size_t)t * HH + jbase + jj] = h;
                    else      ring[(size_t)(t & 1) * HH + jbase + jj] = h;
                }
            }
        }

        // ---- grid barrier (monotonic epoch counter, agent scope) ----
        if (k < TT) {
            __syncthreads();   // all 4 waves drain their stores (vmcnt) + arrive
            if (tid == 0) {
                __threadfence();   // release: flush this XCD's L2 to coherence point
                __hip_atomic_fetch_add(barcnt, 1u, __ATOMIC_ACQ_REL,
                                       __HIP_MEMORY_SCOPE_AGENT);
                const unsigned target = (unsigned)(k + 1) * NWG;
                while (__hip_atomic_load(barcnt, __ATOMIC_ACQUIRE,
                                         __HIP_MEMORY_SCOPE_AGENT) < target)
                    __builtin_amdgcn_s_sleep(2);
                __threadfence();   // acquire: invalidate local L1/L2
            }
            __syncthreads();
        }
    }
}

extern "C" void kernel_launch(void* const* d_in, const int* in_sizes, int n_in,
                              void* d_out, int out_size, void* d_ws, size_t ws_size,
                              hipStream_t stream) {
    (void)in_sizes; (void)n_in; (void)out_size; (void)ws_size;
    const float* x    = (const float*)d_in[0];
    const float* wih0 = (const float*)d_in[1];
    const float* whh0 = (const float*)d_in[2];
    const float* bih0 = (const float*)d_in[3];
    const float* bhh0 = (const float*)d_in[4];
    const float* wih1 = (const float*)d_in[5];
    const float* whh1 = (const float*)d_in[6];
    const float* bih1 = (const float*)d_in[7];
    const float* bhh1 = (const float*)d_in[8];
    float* out = (float*)d_out;

    unsigned* barcnt = (unsigned*)d_ws;                   // [0, 256) bytes
    float*    ring   = (float*)((char*)d_ws + 256);       // 2 * 1024 * 4 B

    // zero the barrier counter every call (graph-capturable, stream-ordered)
    hipMemsetAsync(d_ws, 0, 256, stream);

    hipLaunchKernelGGL(lstm2_persistent, dim3(NWG), dim3(256), 0, stream,
                       x, wih0, whh0, bih0, bhh0,
                       wih1, whh1, bih1, bhh1, out, ring, barcnt);
}

// Round 4
// 27101.187 us; speedup vs baseline: 3.1238x; 3.0592x over previous
//
#include <hip/hip_runtime.h>

#define HH 1024
#define TT 4096
#define NWG 256
#define NWG_PER_LAYER 128
#define JS_PER_WG 8     // 1024 / 128
#define JS_PER_WAVE 2   // 8 j's / 4 waves

__device__ __forceinline__ float fsigmoid(float x) {
    return 1.0f / (1.0f + __expf(-x));
}
__device__ __forceinline__ float ftanh(float x) {
    float ax = fabsf(x);
    float e = __expf(-2.0f * ax);
    float t = (1.0f - e) / (1.0f + e);
    return copysignf(t, x);
}
__device__ __forceinline__ void fma4(float& a, const float4 w, const float4 v) {
    a = fmaf(w.x, v.x, a);
    a = fmaf(w.y, v.y, a);
    a = fmaf(w.z, v.z, a);
    a = fmaf(w.w, v.w, a);
}
// Opaque register pin: "+v" makes the value loop-carried through an opaque op,
// so the allocator must keep it in a VGPR (or pay a spill+reload per step).
__device__ __forceinline__ void pin4(float4& v) {
    asm volatile("" : "+v"(v.x), "+v"(v.y), "+v"(v.z), "+v"(v.w));
}

// LLC-direct (agent-coherent) 16-float load: relaxed atomic 8B loads bypass the
// (non-coherent, possibly stale) L1/L2 and read the coherence point directly.
__device__ __forceinline__ void load16_llc(float4 v[4], const float* p) {
    const unsigned long long* q = (const unsigned long long*)p;
    #pragma unroll
    for (int i = 0; i < 4; ++i) {
        unsigned long long ua = __hip_atomic_load(q + 2 * i,     __ATOMIC_RELAXED, __HIP_MEMORY_SCOPE_AGENT);
        unsigned long long ub = __hip_atomic_load(q + 2 * i + 1, __ATOMIC_RELAXED, __HIP_MEMORY_SCOPE_AGENT);
        float2 a, b;
        __builtin_memcpy(&a, &ua, 8);
        __builtin_memcpy(&b, &ub, 8);
        v[i] = make_float4(a.x, a.y, b.x, b.y);
    }
}

#define FOR_R(F) F(0) F(1) F(2) F(3) F(4) F(5) F(6) F(7)

// Persistent 2-layer LSTM, layers pipelined with skew 1.
// WGs [0,128): layer 0.  WGs [128,256): layer 1. Each wave owns 2 output rows;
// its 16 weight rows (2j x 4 gates x {w_ih,w_hh}) live in 256 NAMED float4
// VGPRs (no alloca -> no scratch). h-vectors are exchanged through LLC via
// relaxed agent atomics (no L2 writeback/invalidate anywhere). Grid sync is a
// 16x16 tree barrier with monotonic epochs; all 256 WGs co-resident (1 WG/CU).
__global__ __launch_bounds__(256, 1) void lstm2_persistent(
    const float* __restrict__ x,
    const float* __restrict__ wih0, const float* __restrict__ whh0,
    const float* __restrict__ bih0, const float* __restrict__ bhh0,
    const float* __restrict__ wih1, const float* __restrict__ whh1,
    const float* __restrict__ bih1, const float* __restrict__ bhh1,
    float* __restrict__ out,     // [T][H]  h2 (output + h2 recurrence buffer)
    float* __restrict__ ring,    // [2][H]  h1 ring (layer0 <-> layer1)
    const float* __restrict__ zbuf,   // [H] zeros (h2[-1])
    unsigned* __restrict__ leaf,      // 16 counters, 128B apart (zeroed)
    unsigned* __restrict__ root)      // 1 counter (zeroed)
{
    const int wg   = blockIdx.x;
    const int tid  = threadIdx.x;
    const int wave = tid >> 6;
    const int lane = tid & 63;
    const bool isL1 = (wg >= NWG_PER_LAYER);
    const int wgl   = isL1 ? (wg - NWG_PER_LAYER) : wg;
    const int jbase = wgl * JS_PER_WG + wave * JS_PER_WAVE;
    const int col   = lane * 16;   // this lane's 16-elem chunk of the 1024-vector

    const float* wih = isL1 ? wih1 : wih0;
    const float* whh = isL1 ? whh1 : whh0;
    const float* bih = isL1 ? bih1 : bih0;
    const float* bhh = isL1 ? bhh1 : bhh0;

    // ---- one-time weight preload into NAMED registers (no arrays!) ----
    #define DECLW(r) float4 WA##r##_0, WA##r##_1, WA##r##_2, WA##r##_3, \
                            WB##r##_0, WB##r##_1, WB##r##_2, WB##r##_3; float B##r;
    FOR_R(DECLW)

    #define LOADW(r) { \
        const int row = ((r) & 3) * HH + (jbase + ((r) >> 2)); \
        const float4* pi = (const float4*)(wih + (size_t)row * HH + col); \
        const float4* ph = (const float4*)(whh + (size_t)row * HH + col); \
        WA##r##_0 = pi[0]; WA##r##_1 = pi[1]; WA##r##_2 = pi[2]; WA##r##_3 = pi[3]; \
        WB##r##_0 = ph[0]; WB##r##_1 = ph[1]; WB##r##_2 = ph[2]; WB##r##_3 = ph[3]; \
        B##r = bih[row] + bhh[row]; }
    FOR_R(LOADW)

    #define PINW(r) pin4(WA##r##_0); pin4(WA##r##_1); pin4(WA##r##_2); pin4(WA##r##_3); \
                    pin4(WB##r##_0); pin4(WB##r##_1); pin4(WB##r##_2); pin4(WB##r##_3); \
                    asm volatile("" : "+v"(B##r));

    float c0v = 0.0f, c1v = 0.0f;

    for (int k = 0; k <= TT; ++k) {
        // Re-pin every iteration: weights become loop-carried opaque values,
        // forcing true VGPR residency (round-3 failure: array->scratch reload).
        FOR_R(PINW)

        const int t = isL1 ? (k - 1) : k;
        if (t >= 0 && t < TT) {
            // input vector: layer0 reads x[t] (plain cached); layer1 reads h1[t] (LLC)
            float4 in4[4];
            if (!isL1) {
                const float4* p = (const float4*)(x + (size_t)t * HH + col);
                in4[0] = p[0]; in4[1] = p[1]; in4[2] = p[2]; in4[3] = p[3];
            } else {
                load16_llc(in4, ring + (size_t)(t & 1) * HH + col);
            }
            // recurrent vector: layer0 -> h1[t-1] (ring), layer1 -> h2[t-1] (out)
            float4 hp4[4];
            load16_llc(hp4, isL1 ? ((t > 0) ? out + (size_t)(t - 1) * HH + col
                                            : zbuf + col)
                                 : ring + (size_t)((t - 1) & 1) * HH + col);

            float acc0, acc1, acc2, acc3, acc4, acc5, acc6, acc7;
            #define DOTW(r) { float a = 0.0f; \
                fma4(a, WA##r##_0, in4[0]); fma4(a, WA##r##_1, in4[1]); \
                fma4(a, WA##r##_2, in4[2]); fma4(a, WA##r##_3, in4[3]); \
                fma4(a, WB##r##_0, hp4[0]); fma4(a, WB##r##_1, hp4[1]); \
                fma4(a, WB##r##_2, hp4[2]); fma4(a, WB##r##_3, hp4[3]); \
                acc##r = a; }
            FOR_R(DOTW)

            // butterfly reduce all 8 accumulators across 64 lanes
            #define REDW(m) \
                acc0 += __shfl_xor(acc0, m, 64); acc1 += __shfl_xor(acc1, m, 64); \
                acc2 += __shfl_xor(acc2, m, 64); acc3 += __shfl_xor(acc3, m, 64); \
                acc4 += __shfl_xor(acc4, m, 64); acc5 += __shfl_xor(acc5, m, 64); \
                acc6 += __shfl_xor(acc6, m, 64); acc7 += __shfl_xor(acc7, m, 64);
            REDW(1) REDW(2) REDW(4) REDW(8) REDW(16) REDW(32)

            // gates (PyTorch order i,f,g,o); c lives in lane 0 only
            const float gi0 = fsigmoid(acc0 + B0), gf0 = fsigmoid(acc1 + B1);
            const float gg0 = ftanh(acc2 + B2),    go0 = fsigmoid(acc3 + B3);
            c0v = gf0 * c0v + gi0 * gg0;
            const float h0 = go0 * ftanh(c0v);
            const float gi1 = fsigmoid(acc4 + B4), gf1 = fsigmoid(acc5 + B5);
            const float gg1 = ftanh(acc6 + B6),    go1 = fsigmoid(acc7 + B7);
            c1v = gf1 * c1v + gi1 * gg1;
            const float h1v = go1 * ftanh(c1v);

            if (lane == 0) {
                float2 hv = make_float2(h0, h1v);   // jbase, jbase+1 (jbase even)
                unsigned long long bits;
                __builtin_memcpy(&bits, &hv, 8);
                float* dstf = isL1 ? (out  + (size_t)t * HH + jbase)
                                   : (ring + (size_t)(t & 1) * HH + jbase);
                __hip_atomic_store((unsigned long long*)dstf, bits,
                                   __ATOMIC_RELAXED, __HIP_MEMORY_SCOPE_AGENT);
            }
        }

        // ---- tree grid barrier (monotonic epochs, no L2 flushes) ----
        if (k < TT) {
            __syncthreads();   // each wave drains its own vmcnt before s_barrier
            if (tid == 0) {
                asm volatile("s_waitcnt vmcnt(0)" ::: "memory");  // h at LLC
                unsigned old = __hip_atomic_fetch_add(&leaf[(wg >> 4) * 32], 1u,
                                   __ATOMIC_RELAXED, __HIP_MEMORY_SCOPE_AGENT);
                if (old == (unsigned)(k * 16 + 15))   // last of 16 WGs in leaf
                    __hip_atomic_fetch_add(root, 1u,
                                   __ATOMIC_RELAXED, __HIP_MEMORY_SCOPE_AGENT);
                const unsigned tgt = (unsigned)((k + 1) * 16);
                while (__hip_atomic_load(root, __ATOMIC_RELAXED,
                                         __HIP_MEMORY_SCOPE_AGENT) < tgt)
                    __builtin_amdgcn_s_sleep(1);
            }
            __syncthreads();
        }
    }
}

extern "C" void kernel_launch(void* const* d_in, const int* in_sizes, int n_in,
                              void* d_out, int out_size, void* d_ws, size_t ws_size,
                              hipStream_t stream) {
    (void)in_sizes; (void)n_in; (void)out_size; (void)ws_size;
    const float* x    = (const float*)d_in[0];
    const float* wih0 = (const float*)d_in[1];
    const float* whh0 = (const float*)d_in[2];
    const float* bih0 = (const float*)d_in[3];
    const float* bhh0 = (const float*)d_in[4];
    const float* wih1 = (const float*)d_in[5];
    const float* whh1 = (const float*)d_in[6];
    const float* bih1 = (const float*)d_in[7];
    const float* bhh1 = (const float*)d_in[8];
    float* out = (float*)d_out;

    // ws layout: [0,2048) leaf counters (16 x 128B) | [2048,2176) root |
    //            [4096,8192) zbuf | [8192,16384) ring
    unsigned* leaf = (unsigned*)d_ws;
    unsigned* root = (unsigned*)((char*)d_ws + 2048);
    float*    zbuf = (float*)((char*)d_ws + 4096);
    float*    ring = (float*)((char*)d_ws + 8192);

    // zero counters + zbuf + ring every call (stream-ordered, graph-capturable)
    hipMemsetAsync(d_ws, 0, 16384, stream);

    hipLaunchKernelGGL(lstm2_persistent, dim3(NWG), dim3(256), 0, stream,
                       x, wih0, whh0, bih0, bhh0,
                       wih1, whh1, bih1, bhh1, out, ring, zbuf, leaf, root);
}

// Round 6
// 22752.455 us; speedup vs baseline: 3.7209x; 1.1911x over previous
//
#include <hip/hip_runtime.h>

#define HH 1024
#define TT 4096
#define NWG 256
#define NWG_PER_LAYER 128
#define JS_PER_WG 8     // 1024 / 128
#define JS_PER_WAVE 2   // 8 j's / 4 waves
#define LDS_BYTES 131072  // 4 waves * 8 rows * 1024 floats * 4 B (w_ih tile)

__device__ __forceinline__ float fsigmoid(float x) {
    return 1.0f / (1.0f + __expf(-x));
}
__device__ __forceinline__ float ftanh(float x) {
    float ax = fabsf(x);
    float e = __expf(-2.0f * ax);
    float t = (1.0f - e) / (1.0f + e);
    return copysignf(t, x);
}
__device__ __forceinline__ void fma4(float& a, const float4 w, const float4 v) {
    a = fmaf(w.x, v.x, a);
    a = fmaf(w.y, v.y, a);
    a = fmaf(w.z, v.z, a);
    a = fmaf(w.w, v.w, a);
}
// Opaque register pin: forces the value to stay live in a VGPR across the loop.
__device__ __forceinline__ void pin4(float4& v) {
    asm volatile("" : "+v"(v.x), "+v"(v.y), "+v"(v.z), "+v"(v.w));
}

// LLC-direct (agent-coherent) 16-float load: relaxed atomic 8B loads bypass the
// (non-coherent, possibly stale) L1/L2 and read the coherence point directly.
__device__ __forceinline__ void load16_llc(float4 v[4], const float* p) {
    const unsigned long long* q = (const unsigned long long*)p;
    #pragma unroll
    for (int i = 0; i < 4; ++i) {
        unsigned long long ua = __hip_atomic_load(q + 2 * i,     __ATOMIC_RELAXED, __HIP_MEMORY_SCOPE_AGENT);
        unsigned long long ub = __hip_atomic_load(q + 2 * i + 1, __ATOMIC_RELAXED, __HIP_MEMORY_SCOPE_AGENT);
        float2 a, b;
        __builtin_memcpy(&a, &ua, 8);
        __builtin_memcpy(&b, &ub, 8);
        v[i] = make_float4(a.x, a.y, b.x, b.y);
    }
}

#define FOR_R(F) F(0) F(1) F(2) F(3) F(4) F(5) F(6) F(7)

// Persistent 2-layer LSTM, layers pipelined with skew 1.
// WGs [0,128): layer 0.  WGs [128,256): layer 1. Each wave owns 2 output rows.
// Storage split (256-arch-VGPR cap makes both matrices in registers impossible):
//   w_hh: 32 named float4 VGPRs/lane (pinned, loop-carried)  -> ~220 VGPR total
//   w_ih: 128 KB dynamic LDS per WG, layout [wave][row][q][lane] (16B lane
//         stride -> dense conflict-free ds_read_b128)
// h-vectors exchanged through LLC via relaxed agent atomics; grid sync is a
// 16x16 tree barrier with monotonic epochs; all 256 WGs co-resident (1 WG/CU).
__global__ __launch_bounds__(256, 1) void lstm2_persistent(
    const float* __restrict__ x,
    const float* __restrict__ wih0, const float* __restrict__ whh0,
    const float* __restrict__ bih0, const float* __restrict__ bhh0,
    const float* __restrict__ wih1, const float* __restrict__ whh1,
    const float* __restrict__ bih1, const float* __restrict__ bhh1,
    float* __restrict__ out,     // [T][H]  h2 (output + h2 recurrence buffer)
    float* __restrict__ ring,    // [2][H]  h1 ring (layer0 <-> layer1)
    const float* __restrict__ zbuf,   // [H] zeros (h2[-1])
    unsigned* __restrict__ leaf,      // 16 counters, 128B apart (zeroed)
    unsigned* __restrict__ root)      // 1 counter (zeroed)
{
    extern __shared__ float ldsw[];   // [4][8][4][256] floats = 128 KB

    const int wg   = blockIdx.x;
    const int tid  = threadIdx.x;
    const int wave = tid >> 6;
    const int lane = tid & 63;
    const bool isL1 = (wg >= NWG_PER_LAYER);
    const int wgl   = isL1 ? (wg - NWG_PER_LAYER) : wg;
    const int jbase = wgl * JS_PER_WG + wave * JS_PER_WAVE;
    const int col   = lane * 16;   // this lane's 16-elem chunk of the 1024-vector

    const float* wih = isL1 ? wih1 : wih0;
    const float* whh = isL1 ? whh1 : whh0;
    const float* bih = isL1 ? bih1 : bih0;
    const float* bhh = isL1 ? bhh1 : bhh0;

    // ---- stage w_ih into LDS: float offset = wave*8192 + r*1024 + q*256 + lane*4
    #pragma unroll
    for (int r = 0; r < 8; ++r) {
        const int row = (r & 3) * HH + (jbase + (r >> 2));
        const float4* p  = (const float4*)(wih + (size_t)row * HH + col);
        float*       wb = ldsw + wave * 8192 + r * 1024 + lane * 4;
        #pragma unroll
        for (int q = 0; q < 4; ++q)
            *(float4*)(wb + q * 256) = p[q];   // FIXED (was q*1024: row overlap)
    }

    // ---- w_hh + bias into NAMED registers (no arrays -> no alloca) ----
    #define DECLW(r) float4 WB##r##_0, WB##r##_1, WB##r##_2, WB##r##_3; float B##r;
    FOR_R(DECLW)

    #define LOADW(r) { \
        const int row = ((r) & 3) * HH + (jbase + ((r) >> 2)); \
        const float4* ph = (const float4*)(whh + (size_t)row * HH + col); \
        WB##r##_0 = ph[0]; WB##r##_1 = ph[1]; WB##r##_2 = ph[2]; WB##r##_3 = ph[3]; \
        B##r = bih[row] + bhh[row]; }
    FOR_R(LOADW)

    #define PINW(r) pin4(WB##r##_0); pin4(WB##r##_1); pin4(WB##r##_2); pin4(WB##r##_3); \
                    asm volatile("" : "+v"(B##r));

    __syncthreads();   // LDS tile ready

    float c0v = 0.0f, c1v = 0.0f;
    int loff = wave * 8192 + lane * 4;   // this lane's LDS float offset

    for (int k = 0; k <= TT; ++k) {
        // Re-pin weight regs + LDS offset every iteration: keeps w_hh truly
        // register-resident and stops LICM from hoisting the 32 LDS loads.
        FOR_R(PINW)
        asm volatile("" : "+v"(loff));

        const int t = isL1 ? (k - 1) : k;
        if (t >= 0 && t < TT) {
            // input vector: layer0 reads x[t] (plain cached); layer1 reads h1[t] (LLC)
            float4 in4[4];
            if (!isL1) {
                const float4* p = (const float4*)(x + (size_t)t * HH + col);
                in4[0] = p[0]; in4[1] = p[1]; in4[2] = p[2]; in4[3] = p[3];
            } else {
                load16_llc(in4, ring + (size_t)(t & 1) * HH + col);
            }
            // recurrent vector: layer0 -> h1[t-1] (ring), layer1 -> h2[t-1] (out)
            float4 hp4[4];
            load16_llc(hp4, isL1 ? ((t > 0) ? out + (size_t)(t - 1) * HH + col
                                            : zbuf + col)
                                 : ring + (size_t)((t - 1) & 1) * HH + col);

            float acc0, acc1, acc2, acc3, acc4, acc5, acc6, acc7;
            #define DOTW(r) { float a = 0.0f; \
                const float4* wp = (const float4*)(ldsw + loff + (r) * 1024); \
                fma4(a, wp[0],   in4[0]); fma4(a, wp[64],  in4[1]); \
                fma4(a, wp[128], in4[2]); fma4(a, wp[192], in4[3]); \
                fma4(a, WB##r##_0, hp4[0]); fma4(a, WB##r##_1, hp4[1]); \
                fma4(a, WB##r##_2, hp4[2]); fma4(a, WB##r##_3, hp4[3]); \
                acc##r = a; }
            FOR_R(DOTW)

            // butterfly reduce all 8 accumulators across 64 lanes
            #define REDW(m) \
                acc0 += __shfl_xor(acc0, m, 64); acc1 += __shfl_xor(acc1, m, 64); \
                acc2 += __shfl_xor(acc2, m, 64); acc3 += __shfl_xor(acc3, m, 64); \
                acc4 += __shfl_xor(acc4, m, 64); acc5 += __shfl_xor(acc5, m, 64); \
                acc6 += __shfl_xor(acc6, m, 64); acc7 += __shfl_xor(acc7, m, 64);
            REDW(1) REDW(2) REDW(4) REDW(8) REDW(16) REDW(32)

            // gates (PyTorch order i,f,g,o)
            const float gi0 = fsigmoid(acc0 + B0), gf0 = fsigmoid(acc1 + B1);
            const float gg0 = ftanh(acc2 + B2),    go0 = fsigmoid(acc3 + B3);
            c0v = gf0 * c0v + gi0 * gg0;
            const float h0 = go0 * ftanh(c0v);
            const float gi1 = fsigmoid(acc4 + B4), gf1 = fsigmoid(acc5 + B5);
            const float gg1 = ftanh(acc6 + B6),    go1 = fsigmoid(acc7 + B7);
            c1v = gf1 * c1v + gi1 * gg1;
            const float h1v = go1 * ftanh(c1v);

            if (lane == 0) {
                float2 hv = make_float2(h0, h1v);   // jbase, jbase+1 (jbase even)
                unsigned long long bits;
                __builtin_memcpy(&bits, &hv, 8);
                float* dstf = isL1 ? (out  + (size_t)t * HH + jbase)
                                   : (ring + (size_t)(t & 1) * HH + jbase);
                __hip_atomic_store((unsigned long long*)dstf, bits,
                                   __ATOMIC_RELAXED, __HIP_MEMORY_SCOPE_AGENT);
            }
        }

        // ---- tree grid barrier (monotonic epochs, no L2 flushes) ----
        if (k < TT) {
            __syncthreads();   // each wave drains its own vmcnt before s_barrier
            if (tid == 0) {
                asm volatile("s_waitcnt vmcnt(0)" ::: "memory");  // h at LLC
                unsigned old = __hip_atomic_fetch_add(&leaf[(wg >> 4) * 32], 1u,
                                   __ATOMIC_RELAXED, __HIP_MEMORY_SCOPE_AGENT);
                if (old == (unsigned)(k * 16 + 15))   // last of 16 WGs in leaf
                    __hip_atomic_fetch_add(root, 1u,
                                   __ATOMIC_RELAXED, __HIP_MEMORY_SCOPE_AGENT);
                const unsigned tgt = (unsigned)((k + 1) * 16);
                while (__hip_atomic_load(root, __ATOMIC_RELAXED,
                                         __HIP_MEMORY_SCOPE_AGENT) < tgt)
                    __builtin_amdgcn_s_sleep(1);
            }
            __syncthreads();
        }
    }
}

extern "C" void kernel_launch(void* const* d_in, const int* in_sizes, int n_in,
                              void* d_out, int out_size, void* d_ws, size_t ws_size,
                              hipStream_t stream) {
    (void)in_sizes; (void)n_in; (void)out_size; (void)ws_size;
    const float* x    = (const float*)d_in[0];
    const float* wih0 = (const float*)d_in[1];
    const float* whh0 = (const float*)d_in[2];
    const float* bih0 = (const float*)d_in[3];
    const float* bhh0 = (const float*)d_in[4];
    const float* wih1 = (const float*)d_in[5];
    const float* whh1 = (const float*)d_in[6];
    const float* bih1 = (const float*)d_in[7];
    const float* bhh1 = (const float*)d_in[8];
    float* out = (float*)d_out;

    // ws layout: [0,2048) leaf counters (16 x 128B) | [2048,2176) root |
    //            [4096,8192) zbuf | [8192,16384) ring
    unsigned* leaf = (unsigned*)d_ws;
    unsigned* root = (unsigned*)((char*)d_ws + 2048);
    float*    zbuf = (float*)((char*)d_ws + 4096);
    float*    ring = (float*)((char*)d_ws + 8192);

    // allow 128 KB dynamic LDS (160 KB available per CU on gfx950)
    hipFuncSetAttribute((const void*)lstm2_persistent,
                        hipFuncAttributeMaxDynamicSharedMemorySize, LDS_BYTES);

    // zero counters + zbuf + ring every call (stream-ordered, graph-capturable)
    hipMemsetAsync(d_ws, 0, 16384, stream);

    hipLaunchKernelGGL(lstm2_persistent, dim3(NWG), dim3(256), LDS_BYTES, stream,
                       x, wih0, whh0, bih0, bhh0,
                       wih1, whh1, bih1, bhh1, out, ring, zbuf, leaf, root);
}